// Round 1
// baseline (373.413 us; speedup 1.0000x reference)
//
#include <hip/hip_runtime.h>

#define B_  32
#define E_  512
#define HW_ 256
#define S_  257
#define NH_ 8
#define HD_ 64

__device__ __forceinline__ float wave_reduce(float v) {
  #pragma unroll
  for (int o = 32; o > 0; o >>= 1) v += __shfl_down(v, o, 64);
  return v;
}

// ---- K1: per-(b,e) spatial mean of complex x ----
__global__ void k_mean(const float* __restrict__ xr, const float* __restrict__ xi,
                       float* __restrict__ mr, float* __restrict__ mi) {
  int wid  = (blockIdx.x * blockDim.x + threadIdx.x) >> 6;   // [0, B*E)
  int lane = threadIdx.x & 63;
  const float* pr = xr + (size_t)wid * HW_;
  const float* pi = xi + (size_t)wid * HW_;
  float sr = 0.f, si = 0.f;
  #pragma unroll
  for (int j = 0; j < HW_; j += 64) { sr += pr[j + lane]; si += pi[j + lane]; }
  sr = wave_reduce(sr); si = wave_reduce(si);
  if (lane == 0) { mr[wid] = sr * (1.f / HW_); mi[wid] = si * (1.f / HW_); }
}

// ---- K2: q0[b,f] = (X[b,0,:] . w_q[f,:] + b_q[f]) / 8  (complex) ----
__global__ void k_q0(const float* __restrict__ mr, const float* __restrict__ mi,
                     const float* __restrict__ pos_r, const float* __restrict__ pos_i,
                     const float* __restrict__ w_in_r, const float* __restrict__ w_in_i,
                     const float* __restrict__ b_in_r, const float* __restrict__ b_in_i,
                     float* __restrict__ q0r, float* __restrict__ q0i) {
  int wid  = (blockIdx.x * blockDim.x + threadIdx.x) >> 6;   // [0, B*E)
  int lane = threadIdx.x & 63;
  int b = wid >> 9, f = wid & (E_ - 1);
  const float* wr = w_in_r + (size_t)f * E_;
  const float* wi = w_in_i + (size_t)f * E_;
  float ar = 0.f, ai = 0.f;
  for (int e = lane; e < E_; e += 64) {
    float Xr = mr[b * E_ + e] + pos_r[(size_t)e * S_];
    float Xi = mi[b * E_ + e] + pos_i[(size_t)e * S_];
    float Cr = wr[e], Ci = wi[e];
    ar += Xr * Cr - Xi * Ci;
    ai += Xr * Ci + Xi * Cr;
  }
  ar = wave_reduce(ar); ai = wave_reduce(ai);
  if (lane == 0) {
    q0r[wid] = (ar + b_in_r[f]) * 0.125f;
    q0i[wid] = (ai + b_in_i[f]) * 0.125f;
  }
}

// ---- K3: u[b,h,e] = sum_d q0[b,h,d] * w_k[h*64+d, e];  c[b,h] = q0[b,h,:] . b_k[h,:] ----
__global__ void k_u(const float* __restrict__ q0r, const float* __restrict__ q0i,
                    const float* __restrict__ w_in_r, const float* __restrict__ w_in_i,
                    const float* __restrict__ b_in_r, const float* __restrict__ b_in_i,
                    float* __restrict__ ur, float* __restrict__ ui,
                    float* __restrict__ cr_, float* __restrict__ ci_) {
  int bh = blockIdx.x;            // [0, B*NH), layout b*NH+h
  int b = bh >> 3, h = bh & 7;
  int e = threadIdx.x;            // 512 threads
  __shared__ float qr[HD_], qi[HD_];
  if (threadIdx.x < HD_) {
    qr[threadIdx.x] = q0r[b * E_ + h * HD_ + threadIdx.x];
    qi[threadIdx.x] = q0i[b * E_ + h * HD_ + threadIdx.x];
  }
  __syncthreads();
  float ar = 0.f, ai = 0.f;
  #pragma unroll 8
  for (int d = 0; d < HD_; ++d) {
    float Wr = w_in_r[(size_t)(E_ + h * HD_ + d) * E_ + e];
    float Wi = w_in_i[(size_t)(E_ + h * HD_ + d) * E_ + e];
    ar += qr[d] * Wr - qi[d] * Wi;
    ai += qr[d] * Wi + qi[d] * Wr;
  }
  ur[(size_t)bh * E_ + e] = ar;
  ui[(size_t)bh * E_ + e] = ai;
  if (threadIdx.x == 0) {
    float sr = 0.f, si = 0.f;
    for (int d = 0; d < HD_; ++d) {
      float br = b_in_r[E_ + h * HD_ + d], bi = b_in_i[E_ + h * HD_ + d];
      sr += qr[d] * br - qi[d] * bi;
      si += qr[d] * bi + qi[d] * br;
    }
    cr_[bh] = sr; ci_[bh] = si;
  }
}

__device__ void softmax257(float* l, float* red, int t) {
  float v = l[t];
  float v256 = l[256];
  red[t] = v; __syncthreads();
  #pragma unroll
  for (int s = 128; s > 0; s >>= 1) { if (t < s) red[t] = fmaxf(red[t], red[t + s]); __syncthreads(); }
  float M = fmaxf(red[0], v256);
  __syncthreads();
  float ex = expf(v - M);
  float e256 = expf(v256 - M);
  red[t] = ex; __syncthreads();
  #pragma unroll
  for (int s = 128; s > 0; s >>= 1) { if (t < s) red[t] += red[t + s]; __syncthreads(); }
  float inv = 1.f / (red[0] + e256);
  __syncthreads();
  l[t] = ex * inv;
  if (t == 0) l[256] = e256 * inv;
  __syncthreads();
}

// ---- K4 (dominant): logits row 0 -> dual softmax -> z[b,h,e] = sum_k w[k]*X[b,k,e] ----
__global__ __launch_bounds__(256) void k_attn(
    const float* __restrict__ xr, const float* __restrict__ xi,
    const float* __restrict__ pos_r, const float* __restrict__ pos_i,
    const float* __restrict__ mr, const float* __restrict__ mi,
    const float* __restrict__ ur, const float* __restrict__ ui,
    const float* __restrict__ cr_, const float* __restrict__ ci_,
    float* __restrict__ zr_, float* __restrict__ zi_) {
  __shared__ float us_r[E_], us_i[E_];
  __shared__ float lr[S_], li[S_];
  __shared__ float red[256];
  int t = threadIdx.x;
  int b = blockIdx.x & 31;      // blockIdx = h*32 + b  (XCD swizzle: heads of b co-located)
  int h = blockIdx.x >> 5;
  int bh = b * NH_ + h;
  us_r[t]       = ur[(size_t)bh * E_ + t];
  us_r[t + 256] = ur[(size_t)bh * E_ + t + 256];
  us_i[t]       = ui[(size_t)bh * E_ + t];
  us_i[t + 256] = ui[(size_t)bh * E_ + t + 256];
  float c_r = cr_[bh], c_i = ci_[bh];
  __syncthreads();

  const float* xrb = xr + (size_t)b * E_ * HW_;
  const float* xib = xi + (size_t)b * E_ * HW_;

  // logits for s = t+1 (coalesced across t)
  float ar = 0.f, ai = 0.f;
  for (int e = 0; e < E_; ++e) {
    float Xr = xrb[e * HW_ + t] + pos_r[(size_t)e * S_ + t + 1];
    float Xi = xib[e * HW_ + t] + pos_i[(size_t)e * S_ + t + 1];
    float Ur = us_r[e], Ui = us_i[e];
    ar += Xr * Ur - Xi * Ui;
    ai += Xr * Ui + Xi * Ur;
  }
  lr[t + 1] = ar + c_r;
  li[t + 1] = ai + c_i;

  // logit for s = 0 (mean token)
  float p0r = 0.f, p0i = 0.f;
  for (int e = t; e < E_; e += 256) {
    float Xr = mr[b * E_ + e] + pos_r[(size_t)e * S_];
    float Xi = mi[b * E_ + e] + pos_i[(size_t)e * S_];
    p0r += Xr * us_r[e] - Xi * us_i[e];
    p0i += Xr * us_i[e] + Xi * us_r[e];
  }
  red[t] = p0r; __syncthreads();
  #pragma unroll
  for (int s = 128; s > 0; s >>= 1) { if (t < s) red[t] += red[t + s]; __syncthreads(); }
  if (t == 0) lr[0] = red[0] + c_r;
  __syncthreads();
  red[t] = p0i; __syncthreads();
  #pragma unroll
  for (int s = 128; s > 0; s >>= 1) { if (t < s) red[t] += red[t + s]; __syncthreads(); }
  if (t == 0) li[0] = red[0] + c_i;
  __syncthreads();

  softmax257(lr, red, t);
  softmax257(li, red, t);

  // z[b,h,e] = sum_k w[k] * X[b,k,e]   (per-thread contiguous x reads)
  #pragma unroll
  for (int pass = 0; pass < 2; ++pass) {
    int e = t + pass * 256;
    const float* xre = xrb + (size_t)e * HW_;
    const float* xie = xib + (size_t)e * HW_;
    const float* pre = pos_r + (size_t)e * S_;
    const float* pie = pos_i + (size_t)e * S_;
    float X0r = mr[b * E_ + e] + pre[0];
    float X0i = mi[b * E_ + e] + pie[0];
    float w0r = lr[0], w0i = li[0];
    float zr = w0r * X0r - w0i * X0i;
    float zi = w0r * X0i + w0i * X0r;
    for (int k = 1; k < S_; ++k) {
      float Xr = xre[k - 1] + pre[k];
      float Xi = xie[k - 1] + pie[k];
      float Wr = lr[k], Wi = li[k];
      zr += Wr * Xr - Wi * Xi;
      zi += Wr * Xi + Wi * Xr;
    }
    zr_[(size_t)bh * E_ + e] = zr;
    zi_[(size_t)bh * E_ + e] = zi;
  }
}

// ---- K5: attn0[b, f=h*64+d] = w_v[f,:] . z[b,h,:] + b_v[f]*(1+i) ----
__global__ void k_v(const float* __restrict__ zr, const float* __restrict__ zi,
                    const float* __restrict__ w_in_r, const float* __restrict__ w_in_i,
                    const float* __restrict__ b_in_r, const float* __restrict__ b_in_i,
                    float* __restrict__ a0r, float* __restrict__ a0i) {
  int wid  = (blockIdx.x * blockDim.x + threadIdx.x) >> 6;   // [0, B*E)
  int lane = threadIdx.x & 63;
  int b = wid >> 9, f = wid & (E_ - 1);
  int h = f >> 6;
  const float* wr  = w_in_r + (size_t)(2 * E_ + f) * E_;
  const float* wi  = w_in_i + (size_t)(2 * E_ + f) * E_;
  const float* zrp = zr + (size_t)(b * NH_ + h) * E_;
  const float* zip = zi + (size_t)(b * NH_ + h) * E_;
  float ar = 0.f, ai = 0.f;
  for (int e = lane; e < E_; e += 64) {
    float Zr = zrp[e], Zi = zip[e], Cr = wr[e], Ci = wi[e];
    ar += Zr * Cr - Zi * Ci;
    ai += Zr * Ci + Zi * Cr;
  }
  ar = wave_reduce(ar); ai = wave_reduce(ai);
  if (lane == 0) {
    float bvr = b_in_r[2 * E_ + f], bvi = b_in_i[2 * E_ + f];
    a0r[wid] = ar + (bvr - bvi);   // sum of complex softmax weights = 1 + i
    a0i[wid] = ai + (bvr + bvi);
  }
}

// ---- K6: generic complex matvec out[b,f] = in[b,:] . w[f,:] + bias[f] ----
__global__ void k_mv(const float* __restrict__ inr, const float* __restrict__ ini,
                     const float* __restrict__ wr_, const float* __restrict__ wi_,
                     const float* __restrict__ br_, const float* __restrict__ bi_,
                     float* __restrict__ outr, float* __restrict__ outi) {
  int wid  = (blockIdx.x * blockDim.x + threadIdx.x) >> 6;   // [0, B*E)
  int lane = threadIdx.x & 63;
  int b = wid >> 9, f = wid & (E_ - 1);
  const float* wr = wr_ + (size_t)f * E_;
  const float* wi = wi_ + (size_t)f * E_;
  const float* ir = inr + (size_t)b * E_;
  const float* ii = ini + (size_t)b * E_;
  float ar = 0.f, ai = 0.f;
  for (int e = lane; e < E_; e += 64) {
    float Xr = ir[e], Xi = ii[e], Cr = wr[e], Ci = wi[e];
    ar += Xr * Cr - Xi * Ci;
    ai += Xr * Ci + Xi * Cr;
  }
  ar = wave_reduce(ar); ai = wave_reduce(ai);
  if (lane == 0) { outr[wid] = ar + br_[f]; outi[wid] = ai + bi_[f]; }
}

// ---- K7: final projection, writes interleaved complex64 output ----
__global__ void k_final(const float* __restrict__ inr, const float* __restrict__ ini,
                        const float* __restrict__ wr_, const float* __restrict__ wi_,
                        const float* __restrict__ br_, const float* __restrict__ bi_,
                        float* __restrict__ out, int interleaved) {
  int wid  = (blockIdx.x * blockDim.x + threadIdx.x) >> 6;   // [0, B*OUT)
  int lane = threadIdx.x & 63;
  int b = wid >> 9, f = wid & (E_ - 1);
  const float* wr = wr_ + (size_t)f * E_;
  const float* wi = wi_ + (size_t)f * E_;
  const float* ir = inr + (size_t)b * E_;
  const float* ii = ini + (size_t)b * E_;
  float ar = 0.f, ai = 0.f;
  for (int e = lane; e < E_; e += 64) {
    float Xr = ir[e], Xi = ii[e], Cr = wr[e], Ci = wi[e];
    ar += Xr * Cr - Xi * Ci;
    ai += Xr * Ci + Xi * Cr;
  }
  ar = wave_reduce(ar); ai = wave_reduce(ai);
  if (lane == 0) {
    float rr = ar + br_[f];
    float im = ai + bi_[f];
    if (interleaved) { out[(size_t)wid * 2] = rr; out[(size_t)wid * 2 + 1] = im; }
    else             { out[wid] = rr; }
  }
}

extern "C" void kernel_launch(void* const* d_in, const int* in_sizes, int n_in,
                              void* d_out, int out_size, void* d_ws, size_t ws_size,
                              hipStream_t stream) {
  (void)in_sizes; (void)n_in; (void)ws_size;
  const float* xr      = (const float*)d_in[0];
  const float* xi      = (const float*)d_in[1];
  const float* pos_r   = (const float*)d_in[2];
  const float* pos_i   = (const float*)d_in[3];
  const float* w_in_r  = (const float*)d_in[4];
  const float* w_in_i  = (const float*)d_in[5];
  const float* b_in_r  = (const float*)d_in[6];
  const float* b_in_i  = (const float*)d_in[7];
  const float* w_out_r = (const float*)d_in[8];
  const float* w_out_i = (const float*)d_in[9];
  const float* b_out_r = (const float*)d_in[10];
  const float* b_out_i = (const float*)d_in[11];
  const float* w_p_r   = (const float*)d_in[12];
  const float* w_p_i   = (const float*)d_in[13];
  const float* b_p_r   = (const float*)d_in[14];
  const float* b_p_i   = (const float*)d_in[15];

  float* ws  = (float*)d_ws;
  float* mr  = ws;                 // B*E
  float* mi  = mr  + B_ * E_;
  float* q0r = mi  + B_ * E_;      // B*E
  float* q0i = q0r + B_ * E_;
  float* ur  = q0i + B_ * E_;      // B*NH*E
  float* ui  = ur  + B_ * NH_ * E_;
  float* cr  = ui  + B_ * NH_ * E_; // B*NH
  float* ci  = cr  + B_ * NH_;
  float* zr  = ci  + B_ * NH_;     // B*NH*E
  float* zi  = zr  + B_ * NH_ * E_;
  float* a0r = zi  + B_ * NH_ * E_; // B*E
  float* a0i = a0r + B_ * E_;
  float* aor = a0i + B_ * E_;       // B*E
  float* aoi = aor + B_ * E_;

  k_mean <<<B_ * E_ / 4, 256, 0, stream>>>(xr, xi, mr, mi);
  k_q0   <<<B_ * E_ / 4, 256, 0, stream>>>(mr, mi, pos_r, pos_i, w_in_r, w_in_i, b_in_r, b_in_i, q0r, q0i);
  k_u    <<<B_ * NH_,    512, 0, stream>>>(q0r, q0i, w_in_r, w_in_i, b_in_r, b_in_i, ur, ui, cr, ci);
  k_attn <<<B_ * NH_,    256, 0, stream>>>(xr, xi, pos_r, pos_i, mr, mi, ur, ui, cr, ci, zr, zi);
  k_v    <<<B_ * E_ / 4, 256, 0, stream>>>(zr, zi, w_in_r, w_in_i, b_in_r, b_in_i, a0r, a0i);
  k_mv   <<<B_ * E_ / 4, 256, 0, stream>>>(a0r, a0i, w_out_r, w_out_i, b_out_r, b_out_i, aor, aoi);
  k_final<<<B_ * E_ / 4, 256, 0, stream>>>(aor, aoi, w_p_r, w_p_i, b_p_r, b_p_i,
                                           (float*)d_out, out_size >= 2 * B_ * E_);
}

// Round 2
// 234.399 us; speedup vs baseline: 1.5931x; 1.5931x over previous
//
#include <hip/hip_runtime.h>

#define B_  32
#define E_  512
#define HW_ 256
#define S_  257
#define NH_ 8
#define HD_ 64
#define EC_ 32
#define NCH_ (E_ / EC_)   // 16

__device__ __forceinline__ float wave_reduce(float v) {
  #pragma unroll
  for (int o = 32; o > 0; o >>= 1) v += __shfl_down(v, o, 64);
  return v;
}

// ---- K1: per-(b,e) spatial mean of complex x ----
__global__ void k_mean(const float* __restrict__ xr, const float* __restrict__ xi,
                       float* __restrict__ mr, float* __restrict__ mi) {
  int wid  = (blockIdx.x * blockDim.x + threadIdx.x) >> 6;   // [0, B*E)
  int lane = threadIdx.x & 63;
  const float* pr = xr + (size_t)wid * HW_;
  const float* pi = xi + (size_t)wid * HW_;
  float sr = 0.f, si = 0.f;
  #pragma unroll
  for (int j = 0; j < HW_; j += 64) { sr += pr[j + lane]; si += pi[j + lane]; }
  sr = wave_reduce(sr); si = wave_reduce(si);
  if (lane == 0) { mr[wid] = sr * (1.f / HW_); mi[wid] = si * (1.f / HW_); }
}

// ---- K2: q0[b,f] = (X[b,0,:] . w_q[f,:] + b_q[f]) / 8  (complex) ----
__global__ void k_q0(const float* __restrict__ mr, const float* __restrict__ mi,
                     const float* __restrict__ pos_r, const float* __restrict__ pos_i,
                     const float* __restrict__ w_in_r, const float* __restrict__ w_in_i,
                     const float* __restrict__ b_in_r, const float* __restrict__ b_in_i,
                     float* __restrict__ q0r, float* __restrict__ q0i) {
  int wid  = (blockIdx.x * blockDim.x + threadIdx.x) >> 6;   // [0, B*E)
  int lane = threadIdx.x & 63;
  int b = wid >> 9, f = wid & (E_ - 1);
  const float* wr = w_in_r + (size_t)f * E_;
  const float* wi = w_in_i + (size_t)f * E_;
  float ar = 0.f, ai = 0.f;
  for (int e = lane; e < E_; e += 64) {
    float Xr = mr[b * E_ + e] + pos_r[(size_t)e * S_];
    float Xi = mi[b * E_ + e] + pos_i[(size_t)e * S_];
    float Cr = wr[e], Ci = wi[e];
    ar += Xr * Cr - Xi * Ci;
    ai += Xr * Ci + Xi * Cr;
  }
  ar = wave_reduce(ar); ai = wave_reduce(ai);
  if (lane == 0) {
    q0r[wid] = (ar + b_in_r[f]) * 0.125f;
    q0i[wid] = (ai + b_in_i[f]) * 0.125f;
  }
}

// ---- K3: u[b,h,e] = sum_d q0[b,h,d] * w_k[h*64+d, e]  (k-bias cancels in softmax) ----
__global__ void k_u(const float* __restrict__ q0r, const float* __restrict__ q0i,
                    const float* __restrict__ w_in_r, const float* __restrict__ w_in_i,
                    float* __restrict__ ur, float* __restrict__ ui) {
  int bh = blockIdx.x;            // [0, B*NH), layout b*NH+h
  int b = bh >> 3, h = bh & 7;
  int e = threadIdx.x;            // 512 threads
  __shared__ float qr[HD_], qi[HD_];
  if (threadIdx.x < HD_) {
    qr[threadIdx.x] = q0r[b * E_ + h * HD_ + threadIdx.x];
    qi[threadIdx.x] = q0i[b * E_ + h * HD_ + threadIdx.x];
  }
  __syncthreads();
  float ar = 0.f, ai = 0.f;
  #pragma unroll 8
  for (int d = 0; d < HD_; ++d) {
    float Wr = w_in_r[(size_t)(E_ + h * HD_ + d) * E_ + e];
    float Wi = w_in_i[(size_t)(E_ + h * HD_ + d) * E_ + e];
    ar += qr[d] * Wr - qi[d] * Wi;
    ai += qr[d] * Wi + qi[d] * Wr;
  }
  ur[(size_t)bh * E_ + e] = ar;
  ui[(size_t)bh * E_ + e] = ai;
}

// ---- K4a: partial logits over e-chunks. block = (b, chunk), all 8 heads ----
__global__ __launch_bounds__(256) void k_logits(
    const float* __restrict__ xr, const float* __restrict__ xi,
    const float* __restrict__ pos_r, const float* __restrict__ pos_i,
    const float* __restrict__ ur, const float* __restrict__ ui,
    float* __restrict__ part) {
  int blk = blockIdx.x;
  int b = blk / NCH_, c = blk % NCH_;
  int t = threadIdx.x;                       // k-1 in [0,256)
  int e0 = c * EC_;
  __shared__ float us[EC_][NH_][2];          // 2 KB
  { int e = t >> 3, h = t & 7;               // EC_*NH_ == 256
    us[e][h][0] = ur[(size_t)(b * NH_ + h) * E_ + e0 + e];
    us[e][h][1] = ui[(size_t)(b * NH_ + h) * E_ + e0 + e]; }
  __syncthreads();
  float ar[NH_], ai[NH_];
  #pragma unroll
  for (int h = 0; h < NH_; ++h) { ar[h] = 0.f; ai[h] = 0.f; }
  const float* xrb = xr + ((size_t)b * E_ + e0) * HW_;
  const float* xib = xi + ((size_t)b * E_ + e0) * HW_;
  #pragma unroll 2
  for (int e = 0; e < EC_; ++e) {
    float Xr = xrb[e * HW_ + t] + pos_r[(size_t)(e0 + e) * S_ + t + 1];
    float Xi = xib[e * HW_ + t] + pos_i[(size_t)(e0 + e) * S_ + t + 1];
    #pragma unroll
    for (int h = 0; h < NH_; ++h) {
      float Ur = us[e][h][0], Ui = us[e][h][1];
      ar[h] += Xr * Ur - Xi * Ui;
      ai[h] += Xr * Ui + Xi * Ur;
    }
  }
  float2* p2 = (float2*)part;
  #pragma unroll
  for (int h = 0; h < NH_; ++h) {
    float2 v; v.x = ar[h]; v.y = ai[h];
    p2[((size_t)(b * NH_ + h) * NCH_ + c) * 256 + t] = v;
  }
}

__device__ void softmax257(float* l, float* red, int t) {
  float v = l[t];
  float v256 = l[256];
  red[t] = v; __syncthreads();
  #pragma unroll
  for (int s = 128; s > 0; s >>= 1) { if (t < s) red[t] = fmaxf(red[t], red[t + s]); __syncthreads(); }
  float M = fmaxf(red[0], v256);
  __syncthreads();
  float ex = expf(v - M);
  float e256 = expf(v256 - M);
  red[t] = ex; __syncthreads();
  #pragma unroll
  for (int s = 128; s > 0; s >>= 1) { if (t < s) red[t] += red[t + s]; __syncthreads(); }
  float inv = 1.f / (red[0] + e256);
  __syncthreads();
  l[t] = ex * inv;
  if (t == 0) l[256] = e256 * inv;
  __syncthreads();
}

// ---- K4b: reduce partials + mean-token logit + dual softmax -> w2[bh][k]=(wr,wi) ----
__global__ __launch_bounds__(256) void k_softmax(
    const float* __restrict__ part,
    const float* __restrict__ mr, const float* __restrict__ mi,
    const float* __restrict__ pos_r, const float* __restrict__ pos_i,
    const float* __restrict__ ur, const float* __restrict__ ui,
    float* __restrict__ w2) {
  int bh = blockIdx.x; int b = bh >> 3;
  int t = threadIdx.x;
  __shared__ float lr[S_], li[S_], red[256];
  const float2* p2 = (const float2*)part + (size_t)bh * NCH_ * 256;
  float sr = 0.f, si = 0.f;
  #pragma unroll
  for (int c = 0; c < NCH_; ++c) { float2 v = p2[c * 256 + t]; sr += v.x; si += v.y; }
  lr[t + 1] = sr; li[t + 1] = si;
  // mean-token logit
  const float* urb = ur + (size_t)bh * E_;
  const float* uib = ui + (size_t)bh * E_;
  float p0r = 0.f, p0i = 0.f;
  for (int e = t; e < E_; e += 256) {
    float Xr = mr[b * E_ + e] + pos_r[(size_t)e * S_];
    float Xi = mi[b * E_ + e] + pos_i[(size_t)e * S_];
    p0r += Xr * urb[e] - Xi * uib[e];
    p0i += Xr * uib[e] + Xi * urb[e];
  }
  red[t] = p0r; __syncthreads();
  #pragma unroll
  for (int s = 128; s > 0; s >>= 1) { if (t < s) red[t] += red[t + s]; __syncthreads(); }
  if (t == 0) lr[0] = red[0];
  __syncthreads();
  red[t] = p0i; __syncthreads();
  #pragma unroll
  for (int s = 128; s > 0; s >>= 1) { if (t < s) red[t] += red[t + s]; __syncthreads(); }
  if (t == 0) li[0] = red[0];
  __syncthreads();
  softmax257(lr, red, t);
  softmax257(li, red, t);
  float2* o = (float2*)w2 + (size_t)bh * S_;
  float2 v; v.x = lr[t]; v.y = li[t]; o[t] = v;
  if (t == 0) { float2 v2; v2.x = lr[256]; v2.y = li[256]; o[256] = v2; }
}

// ---- K4c: z[b,h,e] = sum_k w[b,h,k]*X[b,k,e]. wave per (b,e), lanes split k ----
__global__ __launch_bounds__(256) void k_z(
    const float* __restrict__ xr, const float* __restrict__ xi,
    const float* __restrict__ pos_r, const float* __restrict__ pos_i,
    const float* __restrict__ mr, const float* __restrict__ mi,
    const float* __restrict__ w2,
    float* __restrict__ zr_, float* __restrict__ zi_) {
  __shared__ float2 wls[NH_ * S_];           // 16.4 KB
  int t = threadIdx.x, l = t & 63, w = t >> 6;
  int b = blockIdx.x >> 6;                   // blockIdx = b*64 + g
  int g = blockIdx.x & 63;
  const float2* w2b = (const float2*)w2 + (size_t)b * NH_ * S_;
  for (int i = t; i < NH_ * S_; i += 256) wls[i] = w2b[i];
  __syncthreads();
  #pragma unroll
  for (int r = 0; r < 2; ++r) {
    int e = g * 8 + w * 2 + r;
    const float* xre = xr + ((size_t)b * E_ + e) * HW_;
    const float* xie = xi + ((size_t)b * E_ + e) * HW_;
    const float* pre = pos_r + (size_t)e * S_;
    const float* pie = pos_i + (size_t)e * S_;
    float ar[NH_], ai[NH_];
    #pragma unroll
    for (int h = 0; h < NH_; ++h) { ar[h] = 0.f; ai[h] = 0.f; }
    #pragma unroll
    for (int j = 0; j < 4; ++j) {
      int k = 1 + l + 64 * j;
      float Xr = xre[k - 1] + pre[k];
      float Xi = xie[k - 1] + pie[k];
      #pragma unroll
      for (int h = 0; h < NH_; ++h) {
        float2 W = wls[h * S_ + k];
        ar[h] += W.x * Xr - W.y * Xi;
        ai[h] += W.x * Xi + W.y * Xr;
      }
    }
    #pragma unroll
    for (int h = 0; h < NH_; ++h) { ar[h] = wave_reduce(ar[h]); ai[h] = wave_reduce(ai[h]); }
    if (l == 0) {
      float X0r = mr[b * E_ + e] + pre[0];
      float X0i = mi[b * E_ + e] + pie[0];
      #pragma unroll
      for (int h = 0; h < NH_; ++h) {
        float2 W0 = wls[h * S_];
        zr_[(size_t)(b * NH_ + h) * E_ + e] = ar[h] + W0.x * X0r - W0.y * X0i;
        zi_[(size_t)(b * NH_ + h) * E_ + e] = ai[h] + W0.x * X0i + W0.y * X0r;
      }
    }
  }
}

// ---- K5: attn0[b, f=h*64+d] = w_v[f,:] . z[b,h,:] + b_v[f]*(1+i) ----
__global__ void k_v(const float* __restrict__ zr, const float* __restrict__ zi,
                    const float* __restrict__ w_in_r, const float* __restrict__ w_in_i,
                    const float* __restrict__ b_in_r, const float* __restrict__ b_in_i,
                    float* __restrict__ a0r, float* __restrict__ a0i) {
  int wid  = (blockIdx.x * blockDim.x + threadIdx.x) >> 6;   // [0, B*E)
  int lane = threadIdx.x & 63;
  int b = wid >> 9, f = wid & (E_ - 1);
  int h = f >> 6;
  const float* wr  = w_in_r + (size_t)(2 * E_ + f) * E_;
  const float* wi  = w_in_i + (size_t)(2 * E_ + f) * E_;
  const float* zrp = zr + (size_t)(b * NH_ + h) * E_;
  const float* zip = zi + (size_t)(b * NH_ + h) * E_;
  float ar = 0.f, ai = 0.f;
  for (int e = lane; e < E_; e += 64) {
    float Zr = zrp[e], Zi = zip[e], Cr = wr[e], Ci = wi[e];
    ar += Zr * Cr - Zi * Ci;
    ai += Zr * Ci + Zi * Cr;
  }
  ar = wave_reduce(ar); ai = wave_reduce(ai);
  if (lane == 0) {
    float bvr = b_in_r[2 * E_ + f], bvi = b_in_i[2 * E_ + f];
    a0r[wid] = ar + (bvr - bvi);   // sum of complex softmax weights = 1 + i
    a0i[wid] = ai + (bvr + bvi);
  }
}

// ---- K6: generic complex matvec out[b,f] = in[b,:] . w[f,:] + bias[f] ----
__global__ void k_mv(const float* __restrict__ inr, const float* __restrict__ ini,
                     const float* __restrict__ wr_, const float* __restrict__ wi_,
                     const float* __restrict__ br_, const float* __restrict__ bi_,
                     float* __restrict__ outr, float* __restrict__ outi) {
  int wid  = (blockIdx.x * blockDim.x + threadIdx.x) >> 6;   // [0, B*E)
  int lane = threadIdx.x & 63;
  int b = wid >> 9, f = wid & (E_ - 1);
  const float* wr = wr_ + (size_t)f * E_;
  const float* wi = wi_ + (size_t)f * E_;
  const float* ir = inr + (size_t)b * E_;
  const float* ii = ini + (size_t)b * E_;
  float ar = 0.f, ai = 0.f;
  for (int e = lane; e < E_; e += 64) {
    float Xr = ir[e], Xi = ii[e], Cr = wr[e], Ci = wi[e];
    ar += Xr * Cr - Xi * Ci;
    ai += Xr * Ci + Xi * Cr;
  }
  ar = wave_reduce(ar); ai = wave_reduce(ai);
  if (lane == 0) { outr[wid] = ar + br_[f]; outi[wid] = ai + bi_[f]; }
}

// ---- K7: final projection, writes interleaved complex64 output ----
__global__ void k_final(const float* __restrict__ inr, const float* __restrict__ ini,
                        const float* __restrict__ wr_, const float* __restrict__ wi_,
                        const float* __restrict__ br_, const float* __restrict__ bi_,
                        float* __restrict__ out, int interleaved) {
  int wid  = (blockIdx.x * blockDim.x + threadIdx.x) >> 6;   // [0, B*OUT)
  int lane = threadIdx.x & 63;
  int b = wid >> 9, f = wid & (E_ - 1);
  const float* wr = wr_ + (size_t)f * E_;
  const float* wi = wi_ + (size_t)f * E_;
  const float* ir = inr + (size_t)b * E_;
  const float* ii = ini + (size_t)b * E_;
  float ar = 0.f, ai = 0.f;
  for (int e = lane; e < E_; e += 64) {
    float Xr = ir[e], Xi = ii[e], Cr = wr[e], Ci = wi[e];
    ar += Xr * Cr - Xi * Ci;
    ai += Xr * Ci + Xi * Cr;
  }
  ar = wave_reduce(ar); ai = wave_reduce(ai);
  if (lane == 0) {
    float rr = ar + br_[f];
    float im = ai + bi_[f];
    if (interleaved) { out[(size_t)wid * 2] = rr; out[(size_t)wid * 2 + 1] = im; }
    else             { out[wid] = rr; }
  }
}

extern "C" void kernel_launch(void* const* d_in, const int* in_sizes, int n_in,
                              void* d_out, int out_size, void* d_ws, size_t ws_size,
                              hipStream_t stream) {
  (void)in_sizes; (void)n_in; (void)ws_size;
  const float* xr      = (const float*)d_in[0];
  const float* xi      = (const float*)d_in[1];
  const float* pos_r   = (const float*)d_in[2];
  const float* pos_i   = (const float*)d_in[3];
  const float* w_in_r  = (const float*)d_in[4];
  const float* w_in_i  = (const float*)d_in[5];
  const float* b_in_r  = (const float*)d_in[6];
  const float* b_in_i  = (const float*)d_in[7];
  const float* w_out_r = (const float*)d_in[8];
  const float* w_out_i = (const float*)d_in[9];
  const float* b_out_r = (const float*)d_in[10];
  const float* b_out_i = (const float*)d_in[11];
  const float* w_p_r   = (const float*)d_in[12];
  const float* w_p_i   = (const float*)d_in[13];
  const float* b_p_r   = (const float*)d_in[14];
  const float* b_p_i   = (const float*)d_in[15];

  const int BE = B_ * E_, BHE = B_ * NH_ * E_;
  float* ws   = (float*)d_ws;
  float* mr   = ws;
  float* mi   = mr  + BE;
  float* q0r  = mi  + BE;
  float* q0i  = q0r + BE;
  float* ur   = q0i + BE;
  float* ui   = ur  + BHE;
  float* part = ui  + BHE;                       // B*NH*NCH*256*2 floats
  float* w2   = part + (size_t)B_ * NH_ * NCH_ * 512;
  float* zr   = w2  + (size_t)2 * B_ * NH_ * S_;
  float* zi   = zr  + BHE;
  float* a0r  = zi  + BHE;
  float* a0i  = a0r + BE;
  float* aor  = a0i + BE;
  float* aoi  = aor + BE;

  k_mean   <<<B_ * E_ / 4,  256, 0, stream>>>(xr, xi, mr, mi);
  k_q0     <<<B_ * E_ / 4,  256, 0, stream>>>(mr, mi, pos_r, pos_i, w_in_r, w_in_i, b_in_r, b_in_i, q0r, q0i);
  k_u      <<<B_ * NH_,     512, 0, stream>>>(q0r, q0i, w_in_r, w_in_i, ur, ui);
  k_logits <<<B_ * NCH_,    256, 0, stream>>>(xr, xi, pos_r, pos_i, ur, ui, part);
  k_softmax<<<B_ * NH_,     256, 0, stream>>>(part, mr, mi, pos_r, pos_i, ur, ui, w2);
  k_z      <<<B_ * 64,      256, 0, stream>>>(xr, xi, pos_r, pos_i, mr, mi, w2, zr, zi);
  k_v      <<<B_ * E_ / 4,  256, 0, stream>>>(zr, zi, w_in_r, w_in_i, b_in_r, b_in_i, a0r, a0i);
  k_mv     <<<B_ * E_ / 4,  256, 0, stream>>>(a0r, a0i, w_out_r, w_out_i, b_out_r, b_out_i, aor, aoi);
  k_final  <<<B_ * E_ / 4,  256, 0, stream>>>(aor, aoi, w_p_r, w_p_i, b_p_r, b_p_i,
                                              (float*)d_out, out_size >= 2 * B_ * E_);
}

// Round 3
// 190.444 us; speedup vs baseline: 1.9608x; 1.2308x over previous
//
#include <hip/hip_runtime.h>

#define B_  32
#define E_  512
#define HW_ 256
#define S_  257
#define NH_ 8
#define HD_ 64
#define EC_ 32
#define NCH_ (E_ / EC_)   // 16

__device__ __forceinline__ float wave_reduce(float v) {
  #pragma unroll
  for (int o = 32; o > 0; o >>= 1) v += __shfl_down(v, o, 64);
  return v;
}

// ---- K1: m[b,e] = mean_s x[b,e,s] + pos[e,0]   (pos col 0 folded in here, once,
//      as a wave-uniform scalar load -- NOT a per-lane stride-1028 gather) ----
__global__ void k_mean(const float* __restrict__ xr, const float* __restrict__ xi,
                       const float* __restrict__ pos_r, const float* __restrict__ pos_i,
                       float* __restrict__ mr, float* __restrict__ mi) {
  int wid  = (blockIdx.x * blockDim.x + threadIdx.x) >> 6;   // [0, B*E)
  int lane = threadIdx.x & 63;
  int e = wid & (E_ - 1);
  const float* pr = xr + (size_t)wid * HW_;
  const float* pi = xi + (size_t)wid * HW_;
  float sr = 0.f, si = 0.f;
  #pragma unroll
  for (int j = 0; j < HW_; j += 64) { sr += pr[j + lane]; si += pi[j + lane]; }
  sr = wave_reduce(sr); si = wave_reduce(si);
  if (lane == 0) {
    mr[wid] = sr * (1.f / HW_) + pos_r[(size_t)e * S_];
    mi[wid] = si * (1.f / HW_) + pos_i[(size_t)e * S_];
  }
}

// ---- K2: q0[b,f] = (X0[b,:] . w_q[f,:] + b_q[f]) / 8  (complex), X0 = m ----
__global__ void k_q0(const float* __restrict__ mr, const float* __restrict__ mi,
                     const float* __restrict__ w_in_r, const float* __restrict__ w_in_i,
                     const float* __restrict__ b_in_r, const float* __restrict__ b_in_i,
                     float* __restrict__ q0r, float* __restrict__ q0i) {
  int wid  = (blockIdx.x * blockDim.x + threadIdx.x) >> 6;   // [0, B*E)
  int lane = threadIdx.x & 63;
  int b = wid >> 9, f = wid & (E_ - 1);
  const float* wr = w_in_r + (size_t)f * E_;
  const float* wi = w_in_i + (size_t)f * E_;
  float ar = 0.f, ai = 0.f;
  #pragma unroll
  for (int e = lane; e < E_; e += 64) {
    float Xr = mr[b * E_ + e];
    float Xi = mi[b * E_ + e];
    float Cr = wr[e], Ci = wi[e];
    ar += Xr * Cr - Xi * Ci;
    ai += Xr * Ci + Xi * Cr;
  }
  ar = wave_reduce(ar); ai = wave_reduce(ai);
  if (lane == 0) {
    q0r[wid] = (ar + b_in_r[f]) * 0.125f;
    q0i[wid] = (ai + b_in_i[f]) * 0.125f;
  }
}

// ---- K3: u[b,h,e] = sum_d q0[b,h,d] * w_k[h*64+d, e]  (k-bias cancels in softmax) ----
__global__ void k_u(const float* __restrict__ q0r, const float* __restrict__ q0i,
                    const float* __restrict__ w_in_r, const float* __restrict__ w_in_i,
                    float* __restrict__ ur, float* __restrict__ ui) {
  int bh = blockIdx.x;            // [0, B*NH), layout b*NH+h
  int b = bh >> 3, h = bh & 7;
  int e = threadIdx.x;            // 512 threads
  __shared__ float qr[HD_], qi[HD_];
  if (threadIdx.x < HD_) {
    qr[threadIdx.x] = q0r[b * E_ + h * HD_ + threadIdx.x];
    qi[threadIdx.x] = q0i[b * E_ + h * HD_ + threadIdx.x];
  }
  __syncthreads();
  float ar = 0.f, ai = 0.f;
  #pragma unroll 8
  for (int d = 0; d < HD_; ++d) {
    float Wr = w_in_r[(size_t)(E_ + h * HD_ + d) * E_ + e];
    float Wi = w_in_i[(size_t)(E_ + h * HD_ + d) * E_ + e];
    ar += qr[d] * Wr - qi[d] * Wi;
    ai += qr[d] * Wi + qi[d] * Wr;
  }
  ur[(size_t)bh * E_ + e] = ar;
  ui[(size_t)bh * E_ + e] = ai;
}

// ---- K4a: partial logits over e-chunks. block = (b, chunk), all 8 heads ----
__global__ __launch_bounds__(256) void k_logits(
    const float* __restrict__ xr, const float* __restrict__ xi,
    const float* __restrict__ pos_r, const float* __restrict__ pos_i,
    const float* __restrict__ ur, const float* __restrict__ ui,
    float* __restrict__ part) {
  int blk = blockIdx.x;
  int b = blk / NCH_, c = blk % NCH_;
  int t = threadIdx.x;                       // k-1 in [0,256)
  int e0 = c * EC_;
  __shared__ float us[EC_][NH_][2];          // 2 KB
  { int e = t >> 3, h = t & 7;               // EC_*NH_ == 256
    us[e][h][0] = ur[(size_t)(b * NH_ + h) * E_ + e0 + e];
    us[e][h][1] = ui[(size_t)(b * NH_ + h) * E_ + e0 + e]; }
  __syncthreads();
  float ar[NH_], ai[NH_];
  #pragma unroll
  for (int h = 0; h < NH_; ++h) { ar[h] = 0.f; ai[h] = 0.f; }
  const float* xrb = xr + ((size_t)b * E_ + e0) * HW_;
  const float* xib = xi + ((size_t)b * E_ + e0) * HW_;
  #pragma unroll 2
  for (int e = 0; e < EC_; ++e) {
    float Xr = xrb[e * HW_ + t] + pos_r[(size_t)(e0 + e) * S_ + t + 1];
    float Xi = xib[e * HW_ + t] + pos_i[(size_t)(e0 + e) * S_ + t + 1];
    #pragma unroll
    for (int h = 0; h < NH_; ++h) {
      float Ur = us[e][h][0], Ui = us[e][h][1];
      ar[h] += Xr * Ur - Xi * Ui;
      ai[h] += Xr * Ui + Xi * Ur;
    }
  }
  float2* p2 = (float2*)part;
  #pragma unroll
  for (int h = 0; h < NH_; ++h) {
    float2 v; v.x = ar[h]; v.y = ai[h];
    p2[((size_t)(b * NH_ + h) * NCH_ + c) * 256 + t] = v;
  }
}

__device__ void softmax257(float* l, float* red, int t) {
  float v = l[t];
  float v256 = l[256];
  red[t] = v; __syncthreads();
  #pragma unroll
  for (int s = 128; s > 0; s >>= 1) { if (t < s) red[t] = fmaxf(red[t], red[t + s]); __syncthreads(); }
  float M = fmaxf(red[0], v256);
  __syncthreads();
  float ex = expf(v - M);
  float e256 = expf(v256 - M);
  red[t] = ex; __syncthreads();
  #pragma unroll
  for (int s = 128; s > 0; s >>= 1) { if (t < s) red[t] += red[t + s]; __syncthreads(); }
  float inv = 1.f / (red[0] + e256);
  __syncthreads();
  l[t] = ex * inv;
  if (t == 0) l[256] = e256 * inv;
  __syncthreads();
}

// ---- K4b: reduce partials + mean-token logit + dual softmax -> w2[bh][k]=(wr,wi) ----
__global__ __launch_bounds__(256) void k_softmax(
    const float* __restrict__ part,
    const float* __restrict__ mr, const float* __restrict__ mi,
    const float* __restrict__ ur, const float* __restrict__ ui,
    float* __restrict__ w2) {
  int bh = blockIdx.x; int b = bh >> 3;
  int t = threadIdx.x;
  __shared__ float lr[S_], li[S_], red[256];
  const float2* p2 = (const float2*)part + (size_t)bh * NCH_ * 256;
  float sr = 0.f, si = 0.f;
  #pragma unroll
  for (int c = 0; c < NCH_; ++c) { float2 v = p2[c * 256 + t]; sr += v.x; si += v.y; }
  lr[t + 1] = sr; li[t + 1] = si;
  // mean-token logit (X0 = m, contiguous)
  const float* urb = ur + (size_t)bh * E_;
  const float* uib = ui + (size_t)bh * E_;
  float p0r = 0.f, p0i = 0.f;
  #pragma unroll
  for (int e = t; e < E_; e += 256) {
    float Xr = mr[b * E_ + e];
    float Xi = mi[b * E_ + e];
    p0r += Xr * urb[e] - Xi * uib[e];
    p0i += Xr * uib[e] + Xi * urb[e];
  }
  red[t] = p0r; __syncthreads();
  #pragma unroll
  for (int s = 128; s > 0; s >>= 1) { if (t < s) red[t] += red[t + s]; __syncthreads(); }
  if (t == 0) lr[0] = red[0];
  __syncthreads();
  red[t] = p0i; __syncthreads();
  #pragma unroll
  for (int s = 128; s > 0; s >>= 1) { if (t < s) red[t] += red[t + s]; __syncthreads(); }
  if (t == 0) li[0] = red[0];
  __syncthreads();
  softmax257(lr, red, t);
  softmax257(li, red, t);
  float2* o = (float2*)w2 + (size_t)bh * S_;
  float2 v; v.x = lr[t]; v.y = li[t]; o[t] = v;
  if (t == 0) { float2 v2; v2.x = lr[256]; v2.y = li[256]; o[256] = v2; }
}

// ---- K4c: z[b,h,e] = sum_k w[b,h,k]*X[b,k,e]. wave per (b,e), lanes split k ----
__global__ __launch_bounds__(256) void k_z(
    const float* __restrict__ xr, const float* __restrict__ xi,
    const float* __restrict__ pos_r, const float* __restrict__ pos_i,
    const float* __restrict__ mr, const float* __restrict__ mi,
    const float* __restrict__ w2,
    float* __restrict__ zr_, float* __restrict__ zi_) {
  __shared__ float2 wls[NH_ * S_];           // 16.4 KB
  int t = threadIdx.x, l = t & 63, w = t >> 6;
  int b = blockIdx.x >> 6;                   // blockIdx = b*64 + g
  int g = blockIdx.x & 63;
  const float2* w2b = (const float2*)w2 + (size_t)b * NH_ * S_;
  for (int i = t; i < NH_ * S_; i += 256) wls[i] = w2b[i];
  __syncthreads();
  #pragma unroll
  for (int r = 0; r < 2; ++r) {
    int e = g * 8 + w * 2 + r;
    const float* xre = xr + ((size_t)b * E_ + e) * HW_;
    const float* xie = xi + ((size_t)b * E_ + e) * HW_;
    const float* pre = pos_r + (size_t)e * S_;
    const float* pie = pos_i + (size_t)e * S_;
    float ar[NH_], ai[NH_];
    #pragma unroll
    for (int h = 0; h < NH_; ++h) { ar[h] = 0.f; ai[h] = 0.f; }
    #pragma unroll
    for (int j = 0; j < 4; ++j) {
      int k = 1 + l + 64 * j;
      float Xr = xre[k - 1] + pre[k];
      float Xi = xie[k - 1] + pie[k];
      #pragma unroll
      for (int h = 0; h < NH_; ++h) {
        float2 W = wls[h * S_ + k];
        ar[h] += W.x * Xr - W.y * Xi;
        ai[h] += W.x * Xi + W.y * Xr;
      }
    }
    #pragma unroll
    for (int h = 0; h < NH_; ++h) { ar[h] = wave_reduce(ar[h]); ai[h] = wave_reduce(ai[h]); }
    if (l == 0) {
      float X0r = mr[b * E_ + e];          // m already includes pos col 0
      float X0i = mi[b * E_ + e];
      #pragma unroll
      for (int h = 0; h < NH_; ++h) {
        float2 W0 = wls[h * S_];
        zr_[(size_t)(b * NH_ + h) * E_ + e] = ar[h] + W0.x * X0r - W0.y * X0i;
        zi_[(size_t)(b * NH_ + h) * E_ + e] = ai[h] + W0.x * X0i + W0.y * X0r;
      }
    }
  }
}

// ---- K5: attn0[b, f=h*64+d] = w_v[f,:] . z[b,h,:] + b_v[f]*(1+i) ----
__global__ void k_v(const float* __restrict__ zr, const float* __restrict__ zi,
                    const float* __restrict__ w_in_r, const float* __restrict__ w_in_i,
                    const float* __restrict__ b_in_r, const float* __restrict__ b_in_i,
                    float* __restrict__ a0r, float* __restrict__ a0i) {
  int wid  = (blockIdx.x * blockDim.x + threadIdx.x) >> 6;   // [0, B*E)
  int lane = threadIdx.x & 63;
  int b = wid >> 9, f = wid & (E_ - 1);
  int h = f >> 6;
  const float* wr  = w_in_r + (size_t)(2 * E_ + f) * E_;
  const float* wi  = w_in_i + (size_t)(2 * E_ + f) * E_;
  const float* zrp = zr + (size_t)(b * NH_ + h) * E_;
  const float* zip = zi + (size_t)(b * NH_ + h) * E_;
  float ar = 0.f, ai = 0.f;
  #pragma unroll
  for (int e = lane; e < E_; e += 64) {
    float Zr = zrp[e], Zi = zip[e], Cr = wr[e], Ci = wi[e];
    ar += Zr * Cr - Zi * Ci;
    ai += Zr * Ci + Zi * Cr;
  }
  ar = wave_reduce(ar); ai = wave_reduce(ai);
  if (lane == 0) {
    float bvr = b_in_r[2 * E_ + f], bvi = b_in_i[2 * E_ + f];
    a0r[wid] = ar + (bvr - bvi);   // sum of complex softmax weights = 1 + i
    a0i[wid] = ai + (bvr + bvi);
  }
}

// ---- K6: generic complex matvec out[b,f] = in[b,:] . w[f,:] + bias[f] ----
__global__ void k_mv(const float* __restrict__ inr, const float* __restrict__ ini,
                     const float* __restrict__ wr_, const float* __restrict__ wi_,
                     const float* __restrict__ br_, const float* __restrict__ bi_,
                     float* __restrict__ outr, float* __restrict__ outi) {
  int wid  = (blockIdx.x * blockDim.x + threadIdx.x) >> 6;   // [0, B*E)
  int lane = threadIdx.x & 63;
  int b = wid >> 9, f = wid & (E_ - 1);
  const float* wr = wr_ + (size_t)f * E_;
  const float* wi = wi_ + (size_t)f * E_;
  const float* ir = inr + (size_t)b * E_;
  const float* ii = ini + (size_t)b * E_;
  float ar = 0.f, ai = 0.f;
  #pragma unroll
  for (int e = lane; e < E_; e += 64) {
    float Xr = ir[e], Xi = ii[e], Cr = wr[e], Ci = wi[e];
    ar += Xr * Cr - Xi * Ci;
    ai += Xr * Ci + Xi * Cr;
  }
  ar = wave_reduce(ar); ai = wave_reduce(ai);
  if (lane == 0) { outr[wid] = ar + br_[f]; outi[wid] = ai + bi_[f]; }
}

// ---- K7: final projection, writes interleaved complex64 output ----
__global__ void k_final(const float* __restrict__ inr, const float* __restrict__ ini,
                        const float* __restrict__ wr_, const float* __restrict__ wi_,
                        const float* __restrict__ br_, const float* __restrict__ bi_,
                        float* __restrict__ out, int interleaved) {
  int wid  = (blockIdx.x * blockDim.x + threadIdx.x) >> 6;   // [0, B*OUT)
  int lane = threadIdx.x & 63;
  int b = wid >> 9, f = wid & (E_ - 1);
  const float* wr = wr_ + (size_t)f * E_;
  const float* wi = wi_ + (size_t)f * E_;
  const float* ir = inr + (size_t)b * E_;
  const float* ii = ini + (size_t)b * E_;
  float ar = 0.f, ai = 0.f;
  #pragma unroll
  for (int e = lane; e < E_; e += 64) {
    float Xr = ir[e], Xi = ii[e], Cr = wr[e], Ci = wi[e];
    ar += Xr * Cr - Xi * Ci;
    ai += Xr * Ci + Xi * Cr;
  }
  ar = wave_reduce(ar); ai = wave_reduce(ai);
  if (lane == 0) {
    float rr = ar + br_[f];
    float im = ai + bi_[f];
    if (interleaved) { out[(size_t)wid * 2] = rr; out[(size_t)wid * 2 + 1] = im; }
    else             { out[wid] = rr; }
  }
}

extern "C" void kernel_launch(void* const* d_in, const int* in_sizes, int n_in,
                              void* d_out, int out_size, void* d_ws, size_t ws_size,
                              hipStream_t stream) {
  (void)in_sizes; (void)n_in; (void)ws_size;
  const float* xr      = (const float*)d_in[0];
  const float* xi      = (const float*)d_in[1];
  const float* pos_r   = (const float*)d_in[2];
  const float* pos_i   = (const float*)d_in[3];
  const float* w_in_r  = (const float*)d_in[4];
  const float* w_in_i  = (const float*)d_in[5];
  const float* b_in_r  = (const float*)d_in[6];
  const float* b_in_i  = (const float*)d_in[7];
  const float* w_out_r = (const float*)d_in[8];
  const float* w_out_i = (const float*)d_in[9];
  const float* b_out_r = (const float*)d_in[10];
  const float* b_out_i = (const float*)d_in[11];
  const float* w_p_r   = (const float*)d_in[12];
  const float* w_p_i   = (const float*)d_in[13];
  const float* b_p_r   = (const float*)d_in[14];
  const float* b_p_i   = (const float*)d_in[15];

  const int BE = B_ * E_, BHE = B_ * NH_ * E_;
  float* ws   = (float*)d_ws;
  float* mr   = ws;
  float* mi   = mr  + BE;
  float* q0r  = mi  + BE;
  float* q0i  = q0r + BE;
  float* ur   = q0i + BE;
  float* ui   = ur  + BHE;
  float* part = ui  + BHE;                       // B*NH*NCH*256*2 floats
  float* w2   = part + (size_t)B_ * NH_ * NCH_ * 512;
  float* zr   = w2  + (size_t)2 * B_ * NH_ * S_;
  float* zi   = zr  + BHE;
  float* a0r  = zi  + BHE;
  float* a0i  = a0r + BE;
  float* aor  = a0i + BE;
  float* aoi  = aor + BE;

  k_mean   <<<B_ * E_ / 4,  256, 0, stream>>>(xr, xi, pos_r, pos_i, mr, mi);
  k_q0     <<<B_ * E_ / 4,  256, 0, stream>>>(mr, mi, w_in_r, w_in_i, b_in_r, b_in_i, q0r, q0i);
  k_u      <<<B_ * NH_,     512, 0, stream>>>(q0r, q0i, w_in_r, w_in_i, ur, ui);
  k_logits <<<B_ * NCH_,    256, 0, stream>>>(xr, xi, pos_r, pos_i, ur, ui, part);
  k_softmax<<<B_ * NH_,     256, 0, stream>>>(part, mr, mi, ur, ui, w2);
  k_z      <<<B_ * 64,      256, 0, stream>>>(xr, xi, pos_r, pos_i, mr, mi, w2, zr, zi);
  k_v      <<<B_ * E_ / 4,  256, 0, stream>>>(zr, zi, w_in_r, w_in_i, b_in_r, b_in_i, a0r, a0i);
  k_mv     <<<B_ * E_ / 4,  256, 0, stream>>>(a0r, a0i, w_out_r, w_out_i, b_out_r, b_out_i, aor, aoi);
  k_final  <<<B_ * E_ / 4,  256, 0, stream>>>(aor, aoi, w_p_r, w_p_i, b_p_r, b_p_i,
                                              (float*)d_out, out_size >= 2 * B_ * E_);
}